// Round 15
// baseline (561.892 us; speedup 1.0000x reference)
//
#include <hip/hip_runtime.h>
#include <hip/hip_bf16.h>

// Problem constants
#define B_ 4
#define S_ 2048
#define D_ 1024
#define H_ 16
#define DK_ 64
#define MROWS (B_*S_)   // 8192

typedef unsigned short u16;
typedef unsigned int u32;
typedef __bf16 bf16x8 __attribute__((ext_vector_type(8)));
typedef float f32x4 __attribute__((ext_vector_type(4)));

// async global->LDS, 16B per lane, wave-uniform LDS base + lane*16
#define GLDS16(gp, lp) __builtin_amdgcn_global_load_lds( \
    (__attribute__((address_space(1))) void*)(gp), \
    (__attribute__((address_space(3))) void*)(lp), 16, 0, 0)

__device__ __forceinline__ bf16x8 frag_ld(const u16* p) {
    uint4 u = *reinterpret_cast<const uint4*>(p);
    return __builtin_bit_cast(bf16x8, u);
}
__device__ __forceinline__ u16 f2b(float f) {
    return __builtin_bit_cast(u16, __float2bfloat16(f));
}
// XOR-swizzled offset into a [R][64-u16] LDS tile: logical (row R, u16 col C)
// -> physical u16 offset. 16B chunk index is XORed with (R&7) so the 16 l15
// lanes of a ds_read_b128 spread across all 32 banks.
__device__ __forceinline__ int swzRC(int R, int C) {
    return R * 64 + (C ^ ((R & 7) << 3));
}

// ---------------- fp32 -> bf16 convert (multi-tensor, grid.y selects) ----------------
__global__ __launch_bounds__(256) void cvt_multi(
    const float* __restrict__ s0, u16* __restrict__ d0,
    const float* __restrict__ s1, u16* __restrict__ d1,
    const float* __restrict__ s2, u16* __restrict__ d2,
    const float* __restrict__ s3, u16* __restrict__ d3, int n)
{
    const float* s; u16* d;
    switch (blockIdx.y) {
        case 0:  s = s0; d = d0; break;
        case 1:  s = s1; d = d1; break;
        case 2:  s = s2; d = d2; break;
        default: s = s3; d = d3; break;
    }
    int i = (blockIdx.x * 256 + threadIdx.x) * 4;
    if (i >= n) return;
    float4 f = *reinterpret_cast<const float4*>(s + i);
    ushort4 u;
    u.x = f2b(f.x); u.y = f2b(f.y); u.z = f2b(f.z); u.w = f2b(f.w);
    *reinterpret_cast<ushort4*>(d + i) = u;
}

// ---------------- fused QKV projection GEMM ----------------
// grid (8, 64, 3): z=0 -> Q (row-major bf16), z=1 -> K (row-major bf16),
// z=2 -> V (per-head transposed Vt[(b*H+h)*64+d][S]).
__global__ __launch_bounds__(256) void gemm_qkv(
    const u16* __restrict__ xq, const u16* __restrict__ xk, const u16* __restrict__ xv,
    const u16* __restrict__ wq, const u16* __restrict__ wk, const u16* __restrict__ wv,
    const float* __restrict__ bq, const float* __restrict__ bk, const float* __restrict__ bv,
    u16* __restrict__ qb, u16* __restrict__ kb, u16* __restrict__ vt)
{
    const int K = 1024, N = 1024;
    __shared__ u16 As[128 * 64] __attribute__((aligned(16)));
    __shared__ u16 Bs[128 * 64] __attribute__((aligned(16)));

    int z = blockIdx.z;
    const u16* A; const u16* Bw; const float* bias; u16* outb;
    if (z == 0)      { A = xq; Bw = wq; bias = bq; outb = qb; }
    else if (z == 1) { A = xk; Bw = wk; bias = bk; outb = kb; }
    else             { A = xv; Bw = wv; bias = bv; outb = vt; }

    int lane = threadIdx.x & 63, wid = threadIdx.x >> 6;
    int wr = wid >> 1, wc = wid & 1;
    int l15 = lane & 15, l4 = lane >> 4;
    int row0 = blockIdx.y * 128, col0 = blockIdx.x * 128;
    int lrow = lane >> 3;
    int lcol = (lane & 7) * 8;

    f32x4 acc[4][4] = {};

    for (int kt = 0; kt < K / 64; ++kt) {
        __syncthreads();
        const u16* Abase = A + (size_t)row0 * K + kt * 64;
        const u16* Bbase = Bw + (size_t)col0 * K + kt * 64;
#pragma unroll
        for (int c = 0; c < 4; ++c) {
            int blk = wid * 4 + c;
            GLDS16(Abase + (size_t)(blk * 8 + lrow) * K + lcol, As + blk * 512);
            GLDS16(Bbase + (size_t)(blk * 8 + lrow) * K + lcol, Bs + blk * 512);
        }
        __builtin_amdgcn_s_waitcnt(0);
        __syncthreads();
#pragma unroll
        for (int kk = 0; kk < 2; ++kk) {
            bf16x8 af[4], bfv[4];
#pragma unroll
            for (int i = 0; i < 4; ++i)
                af[i] = frag_ld(As + (wr * 64 + i * 16 + l15) * 64 + kk * 32 + l4 * 8);
#pragma unroll
            for (int j = 0; j < 4; ++j)
                bfv[j] = frag_ld(Bs + (wc * 64 + j * 16 + l15) * 64 + kk * 32 + l4 * 8);
#pragma unroll
            for (int i = 0; i < 4; ++i)
#pragma unroll
                for (int j = 0; j < 4; ++j)
                    acc[i][j] = __builtin_amdgcn_mfma_f32_16x16x32_bf16(
                        af[i], bfv[j], acc[i][j], 0, 0, 0);
        }
    }

#pragma unroll
    for (int j = 0; j < 4; ++j) {
        int c = col0 + wc * 64 + j * 16 + l15;
        float bv4 = bias[c];
#pragma unroll
        for (int i = 0; i < 4; ++i) {
            int r = row0 + wr * 64 + i * 16 + l4 * 4;
            if (z < 2) {
#pragma unroll
                for (int e = 0; e < 4; ++e)
                    outb[(size_t)(r + e) * N + c] = f2b(acc[i][j][e] + bv4);
            } else {
                int h = c >> 6, dd = c & 63, bb = r >> 11, s = r & 2047;
                ushort4 u;
                u.x = f2b(acc[i][j][0] + bv4);
                u.y = f2b(acc[i][j][1] + bv4);
                u.z = f2b(acc[i][j][2] + bv4);
                u.w = f2b(acc[i][j][3] + bv4);
                *reinterpret_cast<ushort4*>(
                    outb + ((size_t)((bb * H_ + h) * DK_ + dd)) * S_ + s) = u;
            }
        }
    }
}

// ---------------- O-projection GEMM: fp32 out = ctx@Wo^T + bo + resid ----------------
__global__ __launch_bounds__(256) void gemm_oproj(
    const u16* __restrict__ A, const u16* __restrict__ Bw,
    const float* __restrict__ bias, const float* __restrict__ resid,
    float* __restrict__ outf)
{
    const int K = 1024, N = 1024;
    __shared__ u16 As[128 * 64] __attribute__((aligned(16)));
    __shared__ u16 Bs[128 * 64] __attribute__((aligned(16)));
    int lane = threadIdx.x & 63, wid = threadIdx.x >> 6;
    int wr = wid >> 1, wc = wid & 1;
    int l15 = lane & 15, l4 = lane >> 4;
    int row0 = blockIdx.y * 128, col0 = blockIdx.x * 128;
    int lrow = lane >> 3;
    int lcol = (lane & 7) * 8;

    f32x4 acc[4][4] = {};

    for (int kt = 0; kt < K / 64; ++kt) {
        __syncthreads();
        const u16* Abase = A + (size_t)row0 * K + kt * 64;
        const u16* Bbase = Bw + (size_t)col0 * K + kt * 64;
#pragma unroll
        for (int c = 0; c < 4; ++c) {
            int blk = wid * 4 + c;
            GLDS16(Abase + (size_t)(blk * 8 + lrow) * K + lcol, As + blk * 512);
            GLDS16(Bbase + (size_t)(blk * 8 + lrow) * K + lcol, Bs + blk * 512);
        }
        __builtin_amdgcn_s_waitcnt(0);
        __syncthreads();
#pragma unroll
        for (int kk = 0; kk < 2; ++kk) {
            bf16x8 af[4], bfv[4];
#pragma unroll
            for (int i = 0; i < 4; ++i)
                af[i] = frag_ld(As + (wr * 64 + i * 16 + l15) * 64 + kk * 32 + l4 * 8);
#pragma unroll
            for (int j = 0; j < 4; ++j)
                bfv[j] = frag_ld(Bs + (wc * 64 + j * 16 + l15) * 64 + kk * 32 + l4 * 8);
#pragma unroll
            for (int i = 0; i < 4; ++i)
#pragma unroll
                for (int j = 0; j < 4; ++j)
                    acc[i][j] = __builtin_amdgcn_mfma_f32_16x16x32_bf16(
                        af[i], bfv[j], acc[i][j], 0, 0, 0);
        }
    }

#pragma unroll
    for (int j = 0; j < 4; ++j) {
        int c = col0 + wc * 64 + j * 16 + l15;
        float bv = bias[c];
#pragma unroll
        for (int i = 0; i < 4; ++i) {
            int r = row0 + wr * 64 + i * 16 + l4 * 4;
#pragma unroll
            for (int e = 0; e < 4; ++e) {
                size_t idx = (size_t)(r + e) * N + c;
                outf[idx] = acc[i][j][e] + bv + resid[idx];
            }
        }
    }
}

// ---------------- fused attention (two-pass, swapped QK^T, NO Pt buffer) -----------
// grid: (S/64, H, B) = 2048 blocks. 4 waves/block, each wave owns 16 q-rows.
// acc col(l15)=q-row, row(l4*4+j)=key; softmax log2-domain, per-lane online,
// one xor{16,32} merge; attn = exp2(a*K2 - off2), nt f32x4 stores.
// NEW (T12-style): P never touches LDS. Each lane packs its 16 P values into
// 8 u32 bf16-pairs (w0/w1[n]); the PV A-fragment (keys consecutive l4*8+e)
// is built with 16 __shfl + 8 selects: srcA = l15 + (l4&1)*32, srcB = srcA+16,
// n-select by l4>>1 (verified lane-by-lane). Removes the Pt barrier (3->2
// barriers/epoch), 6 LDS ops/epoch, and 9.2KB LDS.
// Pass 1 uses KVBLK=128 via K1 aliasing the Ks|Vs union (dead in pass 1);
// pass-2's first top barrier fences the alias. T2 swizzle on K/V tiles.
__global__ __launch_bounds__(256) void attn_fused(
    const u16* __restrict__ Qb, const u16* __restrict__ Kb,
    const u16* __restrict__ Vt, const int* __restrict__ mask,
    float* __restrict__ attn_out, u16* __restrict__ ctx_out)
{
    __shared__ u16 KV[2 * 64 * 64] __attribute__((aligned(16))); // pass2: Ks|Vs; pass1: K1[128][64]
    u16* Ks = KV;
    u16* Vs = KV + 4096;
    u16* K1 = KV;   // pass-1 alias: 128x64 tile (16KB)

    const float K2 = 0.1803368801f;  // 0.125 * log2(e)

    int lane = threadIdx.x & 63, wid = threadIdx.x >> 6;
    int b = blockIdx.z, h = blockIdx.y;
    int q0 = blockIdx.x * 64 + wid * 16;
    int l15 = lane & 15, l4 = lane >> 4;
    int lrow = lane >> 3;                       // 0..7
    int lcolsw = (((lane & 7) ^ lrow)) * 8;     // swizzled source col (u16)

    const u16* KbBase = Kb + (size_t)(b * S_) * D_ + h * DK_;
    const u16* VtBase = Vt + ((size_t)((b * H_ + h) * DK_)) * S_;
    const int* mrow = mask + b * S_;

    auto issueK = [&](int c) {        // 64-row tile into Ks (pass 2)
#pragma unroll
        for (int cc = 0; cc < 2; ++cc) {
            int blk = wid * 2 + cc;
            GLDS16(KbBase + (size_t)(c * 64 + blk * 8 + lrow) * D_ + lcolsw,
                   Ks + blk * 512);
        }
    };
    auto issueV = [&](int c) {
#pragma unroll
        for (int cc = 0; cc < 2; ++cc) {
            int blk = wid * 2 + cc;
            GLDS16(VtBase + (size_t)(blk * 8 + lrow) * S_ + c * 64 + lcolsw,
                   Vs + blk * 512);
        }
    };
    auto issueK1 = [&](int e) {       // 128-row tile into K1 (pass 1)
#pragma unroll
        for (int cc = 0; cc < 4; ++cc) {
            int blk = wid * 4 + cc;   // 16 blocks of 8 rows = 128 rows
            GLDS16(KbBase + (size_t)(e * 128 + blk * 8 + lrow) * D_ + lcolsw,
                   K1 + blk * 512);
        }
    };

    // Q fragments (B-operand: row = lane&15 over this wave's 16 q-rows)
    bf16x8 qf[2];
#pragma unroll
    for (int kk = 0; kk < 2; ++kk)
        qf[kk] = frag_ld(Qb + (size_t)(b * S_ + q0 + l15) * D_ +
                         h * DK_ + kk * 32 + l4 * 8);

    float m2_run = -3.0e38f;   // running max of a*K2 (log2 units)
    float l_run  = 0.f;        // running sum of exp2(s2 - m2)

    // ---- PASS 1: per-lane online max / exp2-sum, KVBLK=128, 16 epochs ----
    for (int e = 0; e < 16; ++e) {
        __syncthreads();                 // prior epoch's K1 reads done
        issueK1(e);
        __builtin_amdgcn_s_waitcnt(0);
        __syncthreads();                 // K1(e) ready

#pragma unroll
        for (int half = 0; half < 2; ++half) {
            int kbase = e * 128 + half * 64;     // key base of this 64-key half
            const u16* Kh = K1 + half * 64 * 64; // rows half*64..+63

            int4 mv[4];
#pragma unroll
            for (int n = 0; n < 4; ++n)
                mv[n] = *reinterpret_cast<const int4*>(mrow + kbase + n * 16 + l4 * 4);

            bf16x8 kf[4][2];
#pragma unroll
            for (int n = 0; n < 4; ++n)
#pragma unroll
                for (int kk = 0; kk < 2; ++kk)
                    kf[n][kk] = frag_ld(&Kh[swzRC(n * 16 + l15, kk * 32 + l4 * 8)]);

            f32x4 a[4] = {};
#pragma unroll
            for (int n = 0; n < 4; ++n) {
                a[n] = __builtin_amdgcn_mfma_f32_16x16x32_bf16(kf[n][0], qf[0], a[n], 0, 0, 0);
                a[n] = __builtin_amdgcn_mfma_f32_16x16x32_bf16(kf[n][1], qf[1], a[n], 0, 0, 0);
            }
            float s2[4][4];
            float mxn[4];
#pragma unroll
            for (int n = 0; n < 4; ++n) {
                int mm[4] = {mv[n].x, mv[n].y, mv[n].z, mv[n].w};
#pragma unroll
                for (int j = 0; j < 4; ++j)
                    s2[n][j] = mm[j] ? a[n][j] * K2 : -1.0e9f;
                mxn[n] = fmaxf(fmaxf(s2[n][0], s2[n][1]), fmaxf(s2[n][2], s2[n][3]));
            }
            float mx = fmaxf(fmaxf(mxn[0], mxn[1]), fmaxf(mxn[2], mxn[3]));
            float mnew = fmaxf(m2_run, mx);
            float en[4];
#pragma unroll
            for (int n = 0; n < 4; ++n)
                en[n] = (__builtin_amdgcn_exp2f(s2[n][0] - mnew) +
                         __builtin_amdgcn_exp2f(s2[n][1] - mnew)) +
                        (__builtin_amdgcn_exp2f(s2[n][2] - mnew) +
                         __builtin_amdgcn_exp2f(s2[n][3] - mnew));
            float add = (en[0] + en[1]) + (en[2] + en[3]);
            l_run = l_run * __builtin_amdgcn_exp2f(m2_run - mnew) + add;
            m2_run = mnew;
        }
    }

    // cross-lane merge over the key-split lanes (xor 16, 32), then fold 1/l:
    // off2 = m2 + log2(l)  =>  P = exp2(a*K2 - off2)
#pragma unroll
    for (int off = 16; off <= 32; off <<= 1) {
        float mo = __shfl_xor(m2_run, off);
        float lo = __shfl_xor(l_run, off);
        float mn = fmaxf(m2_run, mo);
        l_run = l_run * __builtin_amdgcn_exp2f(m2_run - mn) +
                lo * __builtin_amdgcn_exp2f(mo - mn);
        m2_run = mn;
    }
    float off2 = m2_run + __builtin_amdgcn_logf(l_run);

    f32x4 cacc[4] = {};

    // shuffle sources for the P redistribution (fixed per lane)
    int srcA = l15 + ((l4 & 1) << 5);   // l15 + (l4&1)*32
    int srcB = srcA + 16;
    bool hiN = (l4 >> 1) != 0;

    // ---- PASS 2: recompute, write attn (nt f32x4), in-reg P->PA, PV ----
    // First top barrier also fences the K1 -> Ks/Vs alias (pass-1 reads done).
    for (int c = 0; c < 32; ++c) {
        __syncthreads();                 // prior Ks/Vs reads (incl. PV) done
        issueK(c);
        issueV(c);
        __builtin_amdgcn_s_waitcnt(0);
        __syncthreads();                 // Ks/Vs(c) ready

        int4 mv[4];
#pragma unroll
        for (int n = 0; n < 4; ++n)
            mv[n] = *reinterpret_cast<const int4*>(mrow + c * 64 + n * 16 + l4 * 4);

        bf16x8 kf[4][2];
#pragma unroll
        for (int n = 0; n < 4; ++n)
#pragma unroll
            for (int kk = 0; kk < 2; ++kk)
                kf[n][kk] = frag_ld(&Ks[swzRC(n * 16 + l15, kk * 32 + l4 * 8)]);

        u32 w0[4], w1[4];   // packed bf16 pairs: w0[n]=keys(l4*4+0,1), w1[n]=keys(l4*4+2,3) of tile-row n
        {
            f32x4 a[4] = {};
#pragma unroll
            for (int n = 0; n < 4; ++n) {
                a[n] = __builtin_amdgcn_mfma_f32_16x16x32_bf16(kf[n][0], qf[0], a[n], 0, 0, 0);
                a[n] = __builtin_amdgcn_mfma_f32_16x16x32_bf16(kf[n][1], qf[1], a[n], 0, 0, 0);
            }
            int qrow = q0 + l15;
            float* arow = attn_out + ((size_t)((b * H_ + h) * S_ + qrow)) * S_ + c * 64;
#pragma unroll
            for (int n = 0; n < 4; ++n) {
                int mm[4] = {mv[n].x, mv[n].y, mv[n].z, mv[n].w};
                f32x4 at;
                float av[4];
#pragma unroll
                for (int j = 0; j < 4; ++j) {
                    float t = __builtin_amdgcn_exp2f(a[n][j] * K2 - off2);
                    av[j] = mm[j] ? t : 0.0f;
                }
                at[0] = av[0]; at[1] = av[1]; at[2] = av[2]; at[3] = av[3];
                __builtin_nontemporal_store(
                    at, reinterpret_cast<f32x4*>(arow + n * 16 + l4 * 4));
                w0[n] = (u32)f2b(av[0]) | ((u32)f2b(av[1]) << 16);
                w1[n] = (u32)f2b(av[2]) | ((u32)f2b(av[3]) << 16);
            }
        }

        // PV: ctx[q][d] += P[q][key] * Vt[d][key].
        // PA fragment built in-register: lane (l15,l4) needs keys kk*32+l4*8+0..7
        // of q-row l15; sources hold 4-key groups at (l15, s4) with
        // s4 = (l4&1)*2 (+1), value index n = 2kk + (l4>>1).
#pragma unroll
        for (int kk = 0; kk < 2; ++kk) {
            int n0 = 2 * kk, n1 = 2 * kk + 1;
            u32 a00 = (u32)__shfl((int)w0[n0], srcA);
            u32 a01 = (u32)__shfl((int)w1[n0], srcA);
            u32 a02 = (u32)__shfl((int)w0[n0], srcB);
            u32 a03 = (u32)__shfl((int)w1[n0], srcB);
            u32 a10 = (u32)__shfl((int)w0[n1], srcA);
            u32 a11 = (u32)__shfl((int)w1[n1], srcA);
            u32 a12 = (u32)__shfl((int)w0[n1], srcB);
            u32 a13 = (u32)__shfl((int)w1[n1], srcB);
            uint4 pu;
            pu.x = hiN ? a10 : a00;
            pu.y = hiN ? a11 : a01;
            pu.z = hiN ? a12 : a02;
            pu.w = hiN ? a13 : a03;
            bf16x8 pa = __builtin_bit_cast(bf16x8, pu);
#pragma unroll
            for (int n = 0; n < 4; ++n) {
                bf16x8 vb = frag_ld(&Vs[swzRC(n * 16 + l15, kk * 32 + l4 * 8)]);
                cacc[n] = __builtin_amdgcn_mfma_f32_16x16x32_bf16(
                    pa, vb, cacc[n], 0, 0, 0);
            }
        }
    }

    // write ctx (bf16, [b][q][h*64+d]); C/D: col(l15)=d, row(l4*4+j)=q
#pragma unroll
    for (int n = 0; n < 4; ++n)
#pragma unroll
        for (int j = 0; j < 4; ++j)
            ctx_out[(size_t)(b * S_ + q0 + l4 * 4 + j) * D_ +
                    h * DK_ + n * 16 + l15] = f2b(cacc[n][j]);
}

// ---------------- LayerNorm ----------------
__global__ __launch_bounds__(256) void ln_kernel(
    const float* __restrict__ X, const float* __restrict__ gamma,
    const float* __restrict__ beta, float* __restrict__ out)
{
    int row = blockIdx.x;
    int t = threadIdx.x;
    float4 v = *reinterpret_cast<const float4*>(X + (size_t)row * D_ + t * 4);
    float s = v.x + v.y + v.z + v.w;
    float ss = v.x * v.x + v.y * v.y + v.z * v.z + v.w * v.w;
#pragma unroll
    for (int o = 1; o < 64; o <<= 1) {
        s += __shfl_xor(s, o);
        ss += __shfl_xor(ss, o);
    }
    __shared__ float red[8];
    int wid = t >> 6, lane = t & 63;
    if (lane == 0) { red[wid] = s; red[wid + 4] = ss; }
    __syncthreads();
    s = red[0] + red[1] + red[2] + red[3];
    ss = red[4] + red[5] + red[6] + red[7];
    float mu = s * (1.0f / D_);
    float var = ss * (1.0f / D_) - mu * mu;
    float rs = rsqrtf(var + 1e-5f);
    float4 g = *reinterpret_cast<const float4*>(gamma + t * 4);
    float4 be = *reinterpret_cast<const float4*>(beta + t * 4);
    f32x4 o4;
    o4[0] = (v.x - mu) * rs * g.x + be.x;
    o4[1] = (v.y - mu) * rs * g.y + be.y;
    o4[2] = (v.z - mu) * rs * g.z + be.z;
    o4[3] = (v.w - mu) * rs * g.w + be.w;
    __builtin_nontemporal_store(
        o4, reinterpret_cast<f32x4*>(out + (size_t)row * D_ + t * 4));
}

// ---------------- launch ----------------
extern "C" void kernel_launch(void* const* d_in, const int* in_sizes, int n_in,
                              void* d_out, int out_size, void* d_ws, size_t ws_size,
                              hipStream_t stream)
{
    const float* query = (const float*)d_in[0];
    const float* key   = (const float*)d_in[1];
    const float* value = (const float*)d_in[2];
    const int*   mask  = (const int*)d_in[3];
    const float* Wq = (const float*)d_in[4];
    const float* bq = (const float*)d_in[5];
    const float* Wk = (const float*)d_in[6];
    const float* bk = (const float*)d_in[7];
    const float* Wv = (const float*)d_in[8];
    const float* bv = (const float*)d_in[9];
    const float* Wo = (const float*)d_in[10];
    const float* bo = (const float*)d_in[11];
    const float* gamma = (const float*)d_in[12];
    const float* beta  = (const float*)d_in[13];

    char* w = (char*)d_ws;
    const size_t MB = 1024 * 1024;
    u16* xq = (u16*)(w);              // 16MB  (dead after QKV-proj; reused for ctx)
    u16* xk = (u16*)(w + 16 * MB);    // 16MB  (dead after QKV-proj; reused for xf)
    u16* xv = (u16*)(w + 32 * MB);    // 16MB  (dead after QKV-proj; reused for xf)
    u16* wq = (u16*)(w + 48 * MB);
    u16* wk = (u16*)(w + 50 * MB);
    u16* wv = (u16*)(w + 52 * MB);
    u16* wo = (u16*)(w + 54 * MB);
    u16* qb = (u16*)(w + 56 * MB);
    u16* kb = (u16*)(w + 72 * MB);
    u16* vt = (u16*)(w + 88 * MB);
    u16* ctxb = (u16*)(w);            // reuse xq region
    float* xf = (float*)(w + 16 * MB); // reuse xk+xv regions (32MB)

    float* out0 = (float*)d_out;
    float* attn = (float*)d_out + (size_t)B_ * S_ * D_;

    int nBig = MROWS * D_;  // 8388608
    int nW = D_ * D_;       // 1048576

    // inputs q,k,v (grid.y=3) and weights (grid.y=4), each one launch
    dim3 gc1(nBig / 1024, 3);
    cvt_multi<<<gc1, 256, 0, stream>>>(query, xq, key, xk, value, xv, query, xq, nBig);
    dim3 gc2(nW / 1024, 4);
    cvt_multi<<<gc2, 256, 0, stream>>>(Wq, wq, Wk, wk, Wv, wv, Wo, wo, nW);

    dim3 gq(D_ / 128, MROWS / 128, 3);  // fused QKV projections
    gemm_qkv<<<gq, 256, 0, stream>>>(xq, xk, xv, wq, wk, wv, bq, bk, bv, qb, kb, vt);

    dim3 ga(S_ / 64, H_, B_);           // 2048 blocks, QBLK=64
    attn_fused<<<ga, 256, 0, stream>>>(qb, kb, vt, mask, attn, ctxb);

    dim3 gg(D_ / 128, MROWS / 128);
    gemm_oproj<<<gg, 256, 0, stream>>>(ctxb, wo, bo, query, xf);
    ln_kernel<<<MROWS, 256, 0, stream>>>(xf, gamma, beta, out0);
}

// Round 16
// 484.198 us; speedup vs baseline: 1.1605x; 1.1605x over previous
//
#include <hip/hip_runtime.h>
#include <hip/hip_bf16.h>

// Problem constants
#define B_ 4
#define S_ 2048
#define D_ 1024
#define H_ 16
#define DK_ 64
#define MROWS (B_*S_)   // 8192

typedef unsigned short u16;
typedef unsigned int u32;
typedef __bf16 bf16x8 __attribute__((ext_vector_type(8)));
typedef float f32x4 __attribute__((ext_vector_type(4)));

// async global->LDS, 16B per lane, wave-uniform LDS base + lane*16
#define GLDS16(gp, lp) __builtin_amdgcn_global_load_lds( \
    (__attribute__((address_space(1))) void*)(gp), \
    (__attribute__((address_space(3))) void*)(lp), 16, 0, 0)

__device__ __forceinline__ bf16x8 frag_ld(const u16* p) {
    uint4 u = *reinterpret_cast<const uint4*>(p);
    return __builtin_bit_cast(bf16x8, u);
}
__device__ __forceinline__ u16 f2b(float f) {
    return __builtin_bit_cast(u16, __float2bfloat16(f));
}
// XOR-swizzled offset into a [R][64-u16] LDS tile: logical (row R, u16 col C)
// -> physical u16 offset. 16B chunk index is XORed with (R&7) so the 16 l15
// lanes of a ds_read_b128 spread across all 32 banks.
__device__ __forceinline__ int swzRC(int R, int C) {
    return R * 64 + (C ^ ((R & 7) << 3));
}

// ---------------- fp32 -> bf16 convert (multi-tensor, grid.y selects) ----------------
__global__ __launch_bounds__(256) void cvt_multi(
    const float* __restrict__ s0, u16* __restrict__ d0,
    const float* __restrict__ s1, u16* __restrict__ d1,
    const float* __restrict__ s2, u16* __restrict__ d2,
    const float* __restrict__ s3, u16* __restrict__ d3, int n)
{
    const float* s; u16* d;
    switch (blockIdx.y) {
        case 0:  s = s0; d = d0; break;
        case 1:  s = s1; d = d1; break;
        case 2:  s = s2; d = d2; break;
        default: s = s3; d = d3; break;
    }
    int i = (blockIdx.x * 256 + threadIdx.x) * 4;
    if (i >= n) return;
    float4 f = *reinterpret_cast<const float4*>(s + i);
    ushort4 u;
    u.x = f2b(f.x); u.y = f2b(f.y); u.z = f2b(f.z); u.w = f2b(f.w);
    *reinterpret_cast<ushort4*>(d + i) = u;
}

// ---------------- fused QKV projection GEMM ----------------
// grid (8, 64, 3): z=0 -> Q (row-major bf16), z=1 -> K (row-major bf16),
// z=2 -> V (per-head transposed Vt[(b*H+h)*64+d][S]).
__global__ __launch_bounds__(256) void gemm_qkv(
    const u16* __restrict__ xq, const u16* __restrict__ xk, const u16* __restrict__ xv,
    const u16* __restrict__ wq, const u16* __restrict__ wk, const u16* __restrict__ wv,
    const float* __restrict__ bq, const float* __restrict__ bk, const float* __restrict__ bv,
    u16* __restrict__ qb, u16* __restrict__ kb, u16* __restrict__ vt)
{
    const int K = 1024, N = 1024;
    __shared__ u16 As[128 * 64] __attribute__((aligned(16)));
    __shared__ u16 Bs[128 * 64] __attribute__((aligned(16)));

    int z = blockIdx.z;
    const u16* A; const u16* Bw; const float* bias; u16* outb;
    if (z == 0)      { A = xq; Bw = wq; bias = bq; outb = qb; }
    else if (z == 1) { A = xk; Bw = wk; bias = bk; outb = kb; }
    else             { A = xv; Bw = wv; bias = bv; outb = vt; }

    int lane = threadIdx.x & 63, wid = threadIdx.x >> 6;
    int wr = wid >> 1, wc = wid & 1;
    int l15 = lane & 15, l4 = lane >> 4;
    int row0 = blockIdx.y * 128, col0 = blockIdx.x * 128;
    int lrow = lane >> 3;
    int lcol = (lane & 7) * 8;

    f32x4 acc[4][4] = {};

    for (int kt = 0; kt < K / 64; ++kt) {
        __syncthreads();
        const u16* Abase = A + (size_t)row0 * K + kt * 64;
        const u16* Bbase = Bw + (size_t)col0 * K + kt * 64;
#pragma unroll
        for (int c = 0; c < 4; ++c) {
            int blk = wid * 4 + c;
            GLDS16(Abase + (size_t)(blk * 8 + lrow) * K + lcol, As + blk * 512);
            GLDS16(Bbase + (size_t)(blk * 8 + lrow) * K + lcol, Bs + blk * 512);
        }
        __builtin_amdgcn_s_waitcnt(0);
        __syncthreads();
#pragma unroll
        for (int kk = 0; kk < 2; ++kk) {
            bf16x8 af[4], bfv[4];
#pragma unroll
            for (int i = 0; i < 4; ++i)
                af[i] = frag_ld(As + (wr * 64 + i * 16 + l15) * 64 + kk * 32 + l4 * 8);
#pragma unroll
            for (int j = 0; j < 4; ++j)
                bfv[j] = frag_ld(Bs + (wc * 64 + j * 16 + l15) * 64 + kk * 32 + l4 * 8);
#pragma unroll
            for (int i = 0; i < 4; ++i)
#pragma unroll
                for (int j = 0; j < 4; ++j)
                    acc[i][j] = __builtin_amdgcn_mfma_f32_16x16x32_bf16(
                        af[i], bfv[j], acc[i][j], 0, 0, 0);
        }
    }

#pragma unroll
    for (int j = 0; j < 4; ++j) {
        int c = col0 + wc * 64 + j * 16 + l15;
        float bv4 = bias[c];
#pragma unroll
        for (int i = 0; i < 4; ++i) {
            int r = row0 + wr * 64 + i * 16 + l4 * 4;
            if (z < 2) {
#pragma unroll
                for (int e = 0; e < 4; ++e)
                    outb[(size_t)(r + e) * N + c] = f2b(acc[i][j][e] + bv4);
            } else {
                int h = c >> 6, dd = c & 63, bb = r >> 11, s = r & 2047;
                ushort4 u;
                u.x = f2b(acc[i][j][0] + bv4);
                u.y = f2b(acc[i][j][1] + bv4);
                u.z = f2b(acc[i][j][2] + bv4);
                u.w = f2b(acc[i][j][3] + bv4);
                *reinterpret_cast<ushort4*>(
                    outb + ((size_t)((bb * H_ + h) * DK_ + dd)) * S_ + s) = u;
            }
        }
    }
}

// ---------------- O-projection GEMM: fp32 out = ctx@Wo^T + bo + resid ----------------
__global__ __launch_bounds__(256) void gemm_oproj(
    const u16* __restrict__ A, const u16* __restrict__ Bw,
    const float* __restrict__ bias, const float* __restrict__ resid,
    float* __restrict__ outf)
{
    const int K = 1024, N = 1024;
    __shared__ u16 As[128 * 64] __attribute__((aligned(16)));
    __shared__ u16 Bs[128 * 64] __attribute__((aligned(16)));
    int lane = threadIdx.x & 63, wid = threadIdx.x >> 6;
    int wr = wid >> 1, wc = wid & 1;
    int l15 = lane & 15, l4 = lane >> 4;
    int row0 = blockIdx.y * 128, col0 = blockIdx.x * 128;
    int lrow = lane >> 3;
    int lcol = (lane & 7) * 8;

    f32x4 acc[4][4] = {};

    for (int kt = 0; kt < K / 64; ++kt) {
        __syncthreads();
        const u16* Abase = A + (size_t)row0 * K + kt * 64;
        const u16* Bbase = Bw + (size_t)col0 * K + kt * 64;
#pragma unroll
        for (int c = 0; c < 4; ++c) {
            int blk = wid * 4 + c;
            GLDS16(Abase + (size_t)(blk * 8 + lrow) * K + lcol, As + blk * 512);
            GLDS16(Bbase + (size_t)(blk * 8 + lrow) * K + lcol, Bs + blk * 512);
        }
        __builtin_amdgcn_s_waitcnt(0);
        __syncthreads();
#pragma unroll
        for (int kk = 0; kk < 2; ++kk) {
            bf16x8 af[4], bfv[4];
#pragma unroll
            for (int i = 0; i < 4; ++i)
                af[i] = frag_ld(As + (wr * 64 + i * 16 + l15) * 64 + kk * 32 + l4 * 8);
#pragma unroll
            for (int j = 0; j < 4; ++j)
                bfv[j] = frag_ld(Bs + (wc * 64 + j * 16 + l15) * 64 + kk * 32 + l4 * 8);
#pragma unroll
            for (int i = 0; i < 4; ++i)
#pragma unroll
                for (int j = 0; j < 4; ++j)
                    acc[i][j] = __builtin_amdgcn_mfma_f32_16x16x32_bf16(
                        af[i], bfv[j], acc[i][j], 0, 0, 0);
        }
    }

#pragma unroll
    for (int j = 0; j < 4; ++j) {
        int c = col0 + wc * 64 + j * 16 + l15;
        float bv = bias[c];
#pragma unroll
        for (int i = 0; i < 4; ++i) {
            int r = row0 + wr * 64 + i * 16 + l4 * 4;
#pragma unroll
            for (int e = 0; e < 4; ++e) {
                size_t idx = (size_t)(r + e) * N + c;
                outf[idx] = acc[i][j][e] + bv + resid[idx];
            }
        }
    }
}

// ---------------- fused attention (R14 structure + T1 XCD swizzle) ----------------
// grid: (S/64, H, B) = 2048 blocks. 4 waves/block, each wave owns 16 q-rows.
// T1: linear block id L remapped nL = (L&7)*256 + L>>3 (bijective, 2048=8*256):
// each head's 32 q-blocks occupy 32 consecutive nL whose DISPATCH ids stride 8
// -> all on one XCD -> that head's K/V (512KB) stays in one XCD L2 (cuts the
// 8x cross-XCD K/V re-fetch seen as FETCH_SIZE=234MB in R7).
// acc col(l15)=q-row, row(l4*4+j)=key; softmax log2-domain, per-lane online,
// one xor{16,32} merge; attn = exp2(a*K2 - off2), nt f32x4 stores.
// Pass 1 KVBLK=128 via K1 aliasing the Ks|Vs union (dead in pass 1); pass-2's
// first top barrier fences the alias. T2 swizzle on K/V tiles. Pt LDS path,
// barrier-disciplined (R5 race lesson; R15 showed shfl-based P redistribution
// is slower — __shfl = ds_bpermute, same LDS pipe).
__global__ __launch_bounds__(256) void attn_fused(
    const u16* __restrict__ Qb, const u16* __restrict__ Kb,
    const u16* __restrict__ Vt, const int* __restrict__ mask,
    float* __restrict__ attn_out, u16* __restrict__ ctx_out)
{
    __shared__ u16 KV[2 * 64 * 64] __attribute__((aligned(16))); // pass2: Ks|Vs; pass1: K1[128][64]
    __shared__ u16 Pt[64 * 72] __attribute__((aligned(16)));     // bf16 P tile [q][key]
    u16* Ks = KV;
    u16* Vs = KV + 4096;
    u16* K1 = KV;   // pass-1 alias: 128x64 tile (16KB)

    const float K2 = 0.1803368801f;  // 0.125 * log2(e)

    int lane = threadIdx.x & 63, wid = threadIdx.x >> 6;

    // T1 XCD swizzle: decode (bx, h, b) from the remapped linear id
    int L  = blockIdx.x + 32 * (blockIdx.y + 16 * blockIdx.z);
    int nL = (L & 7) * 256 + (L >> 3);
    int bx = nL & 31;
    int h  = (nL >> 5) & 15;
    int b  = nL >> 9;

    int q0 = bx * 64 + wid * 16;
    int l15 = lane & 15, l4 = lane >> 4;
    int lrow = lane >> 3;                       // 0..7
    int lcolsw = (((lane & 7) ^ lrow)) * 8;     // swizzled source col (u16)

    const u16* KbBase = Kb + (size_t)(b * S_) * D_ + h * DK_;
    const u16* VtBase = Vt + ((size_t)((b * H_ + h) * DK_)) * S_;
    const int* mrow = mask + b * S_;

    auto issueK = [&](int c) {        // 64-row tile into Ks (pass 2)
#pragma unroll
        for (int cc = 0; cc < 2; ++cc) {
            int blk = wid * 2 + cc;
            GLDS16(KbBase + (size_t)(c * 64 + blk * 8 + lrow) * D_ + lcolsw,
                   Ks + blk * 512);
        }
    };
    auto issueV = [&](int c) {
#pragma unroll
        for (int cc = 0; cc < 2; ++cc) {
            int blk = wid * 2 + cc;
            GLDS16(VtBase + (size_t)(blk * 8 + lrow) * S_ + c * 64 + lcolsw,
                   Vs + blk * 512);
        }
    };
    auto issueK1 = [&](int e) {       // 128-row tile into K1 (pass 1)
#pragma unroll
        for (int cc = 0; cc < 4; ++cc) {
            int blk = wid * 4 + cc;   // 16 blocks of 8 rows = 128 rows
            GLDS16(KbBase + (size_t)(e * 128 + blk * 8 + lrow) * D_ + lcolsw,
                   K1 + blk * 512);
        }
    };

    // Q fragments (B-operand: row = lane&15 over this wave's 16 q-rows)
    bf16x8 qf[2];
#pragma unroll
    for (int kk = 0; kk < 2; ++kk)
        qf[kk] = frag_ld(Qb + (size_t)(b * S_ + q0 + l15) * D_ +
                         h * DK_ + kk * 32 + l4 * 8);

    float m2_run = -3.0e38f;   // running max of a*K2 (log2 units)
    float l_run  = 0.f;        // running sum of exp2(s2 - m2)

    // ---- PASS 1: per-lane online max / exp2-sum, KVBLK=128, 16 epochs ----
    for (int e = 0; e < 16; ++e) {
        __syncthreads();                 // prior epoch's K1 reads done
        issueK1(e);
        __builtin_amdgcn_s_waitcnt(0);
        __syncthreads();                 // K1(e) ready

#pragma unroll
        for (int half = 0; half < 2; ++half) {
            int kbase = e * 128 + half * 64;     // key base of this 64-key half
            const u16* Kh = K1 + half * 64 * 64; // rows half*64..+63

            int4 mv[4];
#pragma unroll
            for (int n = 0; n < 4; ++n)
                mv[n] = *reinterpret_cast<const int4*>(mrow + kbase + n * 16 + l4 * 4);

            bf16x8 kf[4][2];
#pragma unroll
            for (int n = 0; n < 4; ++n)
#pragma unroll
                for (int kk = 0; kk < 2; ++kk)
                    kf[n][kk] = frag_ld(&Kh[swzRC(n * 16 + l15, kk * 32 + l4 * 8)]);

            f32x4 a[4] = {};
#pragma unroll
            for (int n = 0; n < 4; ++n) {
                a[n] = __builtin_amdgcn_mfma_f32_16x16x32_bf16(kf[n][0], qf[0], a[n], 0, 0, 0);
                a[n] = __builtin_amdgcn_mfma_f32_16x16x32_bf16(kf[n][1], qf[1], a[n], 0, 0, 0);
            }
            float s2[4][4];
            float mxn[4];
#pragma unroll
            for (int n = 0; n < 4; ++n) {
                int mm[4] = {mv[n].x, mv[n].y, mv[n].z, mv[n].w};
#pragma unroll
                for (int j = 0; j < 4; ++j)
                    s2[n][j] = mm[j] ? a[n][j] * K2 : -1.0e9f;
                mxn[n] = fmaxf(fmaxf(s2[n][0], s2[n][1]), fmaxf(s2[n][2], s2[n][3]));
            }
            float mx = fmaxf(fmaxf(mxn[0], mxn[1]), fmaxf(mxn[2], mxn[3]));
            float mnew = fmaxf(m2_run, mx);
            float en[4];
#pragma unroll
            for (int n = 0; n < 4; ++n)
                en[n] = (__builtin_amdgcn_exp2f(s2[n][0] - mnew) +
                         __builtin_amdgcn_exp2f(s2[n][1] - mnew)) +
                        (__builtin_amdgcn_exp2f(s2[n][2] - mnew) +
                         __builtin_amdgcn_exp2f(s2[n][3] - mnew));
            float add = (en[0] + en[1]) + (en[2] + en[3]);
            l_run = l_run * __builtin_amdgcn_exp2f(m2_run - mnew) + add;
            m2_run = mnew;
        }
    }

    // cross-lane merge over the key-split lanes (xor 16, 32), then fold 1/l:
    // off2 = m2 + log2(l)  =>  P = exp2(a*K2 - off2)
#pragma unroll
    for (int off = 16; off <= 32; off <<= 1) {
        float mo = __shfl_xor(m2_run, off);
        float lo = __shfl_xor(l_run, off);
        float mn = fmaxf(m2_run, mo);
        l_run = l_run * __builtin_amdgcn_exp2f(m2_run - mn) +
                lo * __builtin_amdgcn_exp2f(mo - mn);
        m2_run = mn;
    }
    float off2 = m2_run + __builtin_amdgcn_logf(l_run);

    f32x4 cacc[4] = {};

    // ---- PASS 2: recompute, write attn (nt f32x4), Pt, barrier, PV ----
    // First top barrier also fences the K1 -> Ks/Vs alias (pass-1 reads done).
    for (int c = 0; c < 32; ++c) {
        __syncthreads();                 // prior Ks/Vs/Pt reads done
        issueK(c);
        issueV(c);
        __builtin_amdgcn_s_waitcnt(0);
        __syncthreads();                 // Ks/Vs(c) ready

        int4 mv[4];
#pragma unroll
        for (int n = 0; n < 4; ++n)
            mv[n] = *reinterpret_cast<const int4*>(mrow + c * 64 + n * 16 + l4 * 4);

        bf16x8 kf[4][2];
#pragma unroll
        for (int n = 0; n < 4; ++n)
#pragma unroll
            for (int kk = 0; kk < 2; ++kk)
                kf[n][kk] = frag_ld(&Ks[swzRC(n * 16 + l15, kk * 32 + l4 * 8)]);

        {
            f32x4 a[4] = {};
#pragma unroll
            for (int n = 0; n < 4; ++n) {
                a[n] = __builtin_amdgcn_mfma_f32_16x16x32_bf16(kf[n][0], qf[0], a[n], 0, 0, 0);
                a[n] = __builtin_amdgcn_mfma_f32_16x16x32_bf16(kf[n][1], qf[1], a[n], 0, 0, 0);
            }
            int qrow = q0 + l15;
            float* arow = attn_out + ((size_t)((b * H_ + h) * S_ + qrow)) * S_ + c * 64;
            u16* prow = Pt + (wid * 16 + l15) * 72;
#pragma unroll
            for (int n = 0; n < 4; ++n) {
                int mm[4] = {mv[n].x, mv[n].y, mv[n].z, mv[n].w};
                f32x4 at;
                float av[4];
#pragma unroll
                for (int j = 0; j < 4; ++j) {
                    float t = __builtin_amdgcn_exp2f(a[n][j] * K2 - off2);
                    av[j] = mm[j] ? t : 0.0f;
                }
                at[0] = av[0]; at[1] = av[1]; at[2] = av[2]; at[3] = av[3];
                __builtin_nontemporal_store(
                    at, reinterpret_cast<f32x4*>(arow + n * 16 + l4 * 4));
                ushort4 pw;
                pw.x = f2b(av[0]); pw.y = f2b(av[1]);
                pw.z = f2b(av[2]); pw.w = f2b(av[3]);
                *reinterpret_cast<ushort4*>(prow + n * 16 + l4 * 4) = pw;
            }
        }

        // Barrier-discipline Pt: all P writes land before any PV read.
        __syncthreads();

        // PV: ctx[q][d] += P[q][key] * Vt[d][key]
#pragma unroll
        for (int kk = 0; kk < 2; ++kk) {
            bf16x8 pa = frag_ld(Pt + (wid * 16 + l15) * 72 + kk * 32 + l4 * 8);
#pragma unroll
            for (int n = 0; n < 4; ++n) {
                bf16x8 vb = frag_ld(&Vs[swzRC(n * 16 + l15, kk * 32 + l4 * 8)]);
                cacc[n] = __builtin_amdgcn_mfma_f32_16x16x32_bf16(
                    pa, vb, cacc[n], 0, 0, 0);
            }
        }
    }

    // write ctx (bf16, [b][q][h*64+d]); C/D: col(l15)=d, row(l4*4+j)=q
#pragma unroll
    for (int n = 0; n < 4; ++n)
#pragma unroll
        for (int j = 0; j < 4; ++j)
            ctx_out[(size_t)(b * S_ + q0 + l4 * 4 + j) * D_ +
                    h * DK_ + n * 16 + l15] = f2b(cacc[n][j]);
}

// ---------------- LayerNorm ----------------
__global__ __launch_bounds__(256) void ln_kernel(
    const float* __restrict__ X, const float* __restrict__ gamma,
    const float* __restrict__ beta, float* __restrict__ out)
{
    int row = blockIdx.x;
    int t = threadIdx.x;
    float4 v = *reinterpret_cast<const float4*>(X + (size_t)row * D_ + t * 4);
    float s = v.x + v.y + v.z + v.w;
    float ss = v.x * v.x + v.y * v.y + v.z * v.z + v.w * v.w;
#pragma unroll
    for (int o = 1; o < 64; o <<= 1) {
        s += __shfl_xor(s, o);
        ss += __shfl_xor(ss, o);
    }
    __shared__ float red[8];
    int wid = t >> 6, lane = t & 63;
    if (lane == 0) { red[wid] = s; red[wid + 4] = ss; }
    __syncthreads();
    s = red[0] + red[1] + red[2] + red[3];
    ss = red[4] + red[5] + red[6] + red[7];
    float mu = s * (1.0f / D_);
    float var = ss * (1.0f / D_) - mu * mu;
    float rs = rsqrtf(var + 1e-5f);
    float4 g = *reinterpret_cast<const float4*>(gamma + t * 4);
    float4 be = *reinterpret_cast<const float4*>(beta + t * 4);
    f32x4 o4;
    o4[0] = (v.x - mu) * rs * g.x + be.x;
    o4[1] = (v.y - mu) * rs * g.y + be.y;
    o4[2] = (v.z - mu) * rs * g.z + be.z;
    o4[3] = (v.w - mu) * rs * g.w + be.w;
    __builtin_nontemporal_store(
        o4, reinterpret_cast<f32x4*>(out + (size_t)row * D_ + t * 4));
}

// ---------------- launch ----------------
extern "C" void kernel_launch(void* const* d_in, const int* in_sizes, int n_in,
                              void* d_out, int out_size, void* d_ws, size_t ws_size,
                              hipStream_t stream)
{
    const float* query = (const float*)d_in[0];
    const float* key   = (const float*)d_in[1];
    const float* value = (const float*)d_in[2];
    const int*   mask  = (const int*)d_in[3];
    const float* Wq = (const float*)d_in[4];
    const float* bq = (const float*)d_in[5];
    const float* Wk = (const float*)d_in[6];
    const float* bk = (const float*)d_in[7];
    const float* Wv = (const float*)d_in[8];
    const float* bv = (const float*)d_in[9];
    const float* Wo = (const float*)d_in[10];
    const float* bo = (const float*)d_in[11];
    const float* gamma = (const float*)d_in[12];
    const float* beta  = (const float*)d_in[13];

    char* w = (char*)d_ws;
    const size_t MB = 1024 * 1024;
    u16* xq = (u16*)(w);              // 16MB  (dead after QKV-proj; reused for ctx)
    u16* xk = (u16*)(w + 16 * MB);    // 16MB  (dead after QKV-proj; reused for xf)
    u16* xv = (u16*)(w + 32 * MB);    // 16MB  (dead after QKV-proj; reused for xf)
    u16* wq = (u16*)(w + 48 * MB);
    u16* wk = (u16*)(w + 50 * MB);
    u16* wv = (u16*)(w + 52 * MB);
    u16* wo = (u16*)(w + 54 * MB);
    u16* qb = (u16*)(w + 56 * MB);
    u16* kb = (u16*)(w + 72 * MB);
    u16* vt = (u16*)(w + 88 * MB);
    u16* ctxb = (u16*)(w);            // reuse xq region
    float* xf = (float*)(w + 16 * MB); // reuse xk+xv regions (32MB)

    float* out0 = (float*)d_out;
    float* attn = (float*)d_out + (size_t)B_ * S_ * D_;

    int nBig = MROWS * D_;  // 8388608
    int nW = D_ * D_;       // 1048576

    // inputs q,k,v (grid.y=3) and weights (grid.y=4), each one launch
    dim3 gc1(nBig / 1024, 3);
    cvt_multi<<<gc1, 256, 0, stream>>>(query, xq, key, xk, value, xv, query, xq, nBig);
    dim3 gc2(nW / 1024, 4);
    cvt_multi<<<gc2, 256, 0, stream>>>(Wq, wq, Wk, wk, Wv, wv, Wo, wo, nW);

    dim3 gq(D_ / 128, MROWS / 128, 3);  // fused QKV projections
    gemm_qkv<<<gq, 256, 0, stream>>>(xq, xk, xv, wq, wk, wv, bq, bk, bv, qb, kb, vt);

    dim3 ga(S_ / 64, H_, B_);           // 2048 blocks, QBLK=64 (T1-swizzled in-kernel)
    attn_fused<<<ga, 256, 0, stream>>>(qb, kb, vt, mask, attn, ctxb);

    dim3 gg(D_ / 128, MROWS / 128);
    gemm_oproj<<<gg, 256, 0, stream>>>(ctxb, wo, bo, query, xf);
    ln_kernel<<<MROWS, 256, 0, stream>>>(xf, gamma, beta, out0);
}

// Round 17
// 482.884 us; speedup vs baseline: 1.1636x; 1.0027x over previous
//
#include <hip/hip_runtime.h>
#include <hip/hip_bf16.h>

// Problem constants
#define B_ 4
#define S_ 2048
#define D_ 1024
#define H_ 16
#define DK_ 64
#define MROWS (B_*S_)   // 8192

typedef unsigned short u16;
typedef unsigned int u32;
typedef __bf16 bf16x8 __attribute__((ext_vector_type(8)));
typedef float f32x4 __attribute__((ext_vector_type(4)));

// async global->LDS, 16B per lane, wave-uniform LDS base + lane*16
#define GLDS16(gp, lp) __builtin_amdgcn_global_load_lds( \
    (__attribute__((address_space(1))) void*)(gp), \
    (__attribute__((address_space(3))) void*)(lp), 16, 0, 0)

__device__ __forceinline__ bf16x8 frag_ld(const u16* p) {
    uint4 u = *reinterpret_cast<const uint4*>(p);
    return __builtin_bit_cast(bf16x8, u);
}
__device__ __forceinline__ u16 f2b(float f) {
    return __builtin_bit_cast(u16, __float2bfloat16(f));
}
// XOR-swizzled offset into a [R][64-u16] LDS tile: logical (row R, u16 col C)
// -> physical u16 offset. 16B chunk index is XORed with (R&7) so the 16 l15
// lanes of a ds_read_b128 spread across all 32 banks.
__device__ __forceinline__ int swzRC(int R, int C) {
    return R * 64 + (C ^ ((R & 7) << 3));
}

// ---------------- fp32 -> bf16 convert (multi-tensor, grid.y selects) ----------------
__global__ __launch_bounds__(256) void cvt_multi(
    const float* __restrict__ s0, u16* __restrict__ d0,
    const float* __restrict__ s1, u16* __restrict__ d1,
    const float* __restrict__ s2, u16* __restrict__ d2,
    const float* __restrict__ s3, u16* __restrict__ d3, int n)
{
    const float* s; u16* d;
    switch (blockIdx.y) {
        case 0:  s = s0; d = d0; break;
        case 1:  s = s1; d = d1; break;
        case 2:  s = s2; d = d2; break;
        default: s = s3; d = d3; break;
    }
    int i = (blockIdx.x * 256 + threadIdx.x) * 4;
    if (i >= n) return;
    float4 f = *reinterpret_cast<const float4*>(s + i);
    ushort4 u;
    u.x = f2b(f.x); u.y = f2b(f.y); u.z = f2b(f.z); u.w = f2b(f.w);
    *reinterpret_cast<ushort4*>(d + i) = u;
}

// ---------------- fused QKV projection GEMM (T1 XCD-swizzled) ----------------
// grid (8, 64, 3): z=0 -> Q (row-major bf16), z=1 -> K (row-major bf16),
// z=2 -> V (per-head transposed Vt[(b*H+h)*64+d][S]).
// XCD swizzle: linear L (x-fastest) -> nL = (L%8)*192 + L/8 (bijective,
// 1536 = 8*192). XCD = L%8 owns 24 consecutive (z,y) A-panels read by all 8
// x-blocks (adjacent nL -> co-resident) -> A-panel L2-local instead of each
// XCD streaming the full 48MB of activations (R16 attn lesson applied).
__global__ __launch_bounds__(256) void gemm_qkv(
    const u16* __restrict__ xq, const u16* __restrict__ xk, const u16* __restrict__ xv,
    const u16* __restrict__ wq, const u16* __restrict__ wk, const u16* __restrict__ wv,
    const float* __restrict__ bq, const float* __restrict__ bk, const float* __restrict__ bv,
    u16* __restrict__ qb, u16* __restrict__ kb, u16* __restrict__ vt)
{
    const int K = 1024, N = 1024;
    __shared__ u16 As[128 * 64] __attribute__((aligned(16)));
    __shared__ u16 Bs[128 * 64] __attribute__((aligned(16)));

    // XCD-aware remap (work identity depends only on nL; bijective)
    int L  = blockIdx.x + 8 * (blockIdx.y + 64 * blockIdx.z);
    int nL = (L & 7) * 192 + (L >> 3);
    int x_ = nL & 7;
    int y_ = (nL >> 3) & 63;
    int z  = nL >> 9;

    const u16* A; const u16* Bw; const float* bias; u16* outb;
    if (z == 0)      { A = xq; Bw = wq; bias = bq; outb = qb; }
    else if (z == 1) { A = xk; Bw = wk; bias = bk; outb = kb; }
    else             { A = xv; Bw = wv; bias = bv; outb = vt; }

    int lane = threadIdx.x & 63, wid = threadIdx.x >> 6;
    int wr = wid >> 1, wc = wid & 1;
    int l15 = lane & 15, l4 = lane >> 4;
    int row0 = y_ * 128, col0 = x_ * 128;
    int lrow = lane >> 3;
    int lcol = (lane & 7) * 8;

    f32x4 acc[4][4] = {};

    for (int kt = 0; kt < K / 64; ++kt) {
        __syncthreads();
        const u16* Abase = A + (size_t)row0 * K + kt * 64;
        const u16* Bbase = Bw + (size_t)col0 * K + kt * 64;
#pragma unroll
        for (int c = 0; c < 4; ++c) {
            int blk = wid * 4 + c;
            GLDS16(Abase + (size_t)(blk * 8 + lrow) * K + lcol, As + blk * 512);
            GLDS16(Bbase + (size_t)(blk * 8 + lrow) * K + lcol, Bs + blk * 512);
        }
        __builtin_amdgcn_s_waitcnt(0);
        __syncthreads();
#pragma unroll
        for (int kk = 0; kk < 2; ++kk) {
            bf16x8 af[4], bfv[4];
#pragma unroll
            for (int i = 0; i < 4; ++i)
                af[i] = frag_ld(As + (wr * 64 + i * 16 + l15) * 64 + kk * 32 + l4 * 8);
#pragma unroll
            for (int j = 0; j < 4; ++j)
                bfv[j] = frag_ld(Bs + (wc * 64 + j * 16 + l15) * 64 + kk * 32 + l4 * 8);
#pragma unroll
            for (int i = 0; i < 4; ++i)
#pragma unroll
                for (int j = 0; j < 4; ++j)
                    acc[i][j] = __builtin_amdgcn_mfma_f32_16x16x32_bf16(
                        af[i], bfv[j], acc[i][j], 0, 0, 0);
        }
    }

#pragma unroll
    for (int j = 0; j < 4; ++j) {
        int c = col0 + wc * 64 + j * 16 + l15;
        float bv4 = bias[c];
#pragma unroll
        for (int i = 0; i < 4; ++i) {
            int r = row0 + wr * 64 + i * 16 + l4 * 4;
            if (z < 2) {
#pragma unroll
                for (int e = 0; e < 4; ++e)
                    outb[(size_t)(r + e) * N + c] = f2b(acc[i][j][e] + bv4);
            } else {
                int h = c >> 6, dd = c & 63, bb = r >> 11, s = r & 2047;
                ushort4 u;
                u.x = f2b(acc[i][j][0] + bv4);
                u.y = f2b(acc[i][j][1] + bv4);
                u.z = f2b(acc[i][j][2] + bv4);
                u.w = f2b(acc[i][j][3] + bv4);
                *reinterpret_cast<ushort4*>(
                    outb + ((size_t)((bb * H_ + h) * DK_ + dd)) * S_ + s) = u;
            }
        }
    }
}

// ---------------- O-projection GEMM (T1 XCD-swizzled): out = ctx@Wo^T + bo + resid --
// XCD swizzle: nL = (L%8)*64 + L/8 (bijective, 512 = 8*64). Each XCD owns
// 8 consecutive y-panels (2MB A) x all 8 x (2MB B) = exact 4MB L2 fit.
__global__ __launch_bounds__(256) void gemm_oproj(
    const u16* __restrict__ A, const u16* __restrict__ Bw,
    const float* __restrict__ bias, const float* __restrict__ resid,
    float* __restrict__ outf)
{
    const int K = 1024, N = 1024;
    __shared__ u16 As[128 * 64] __attribute__((aligned(16)));
    __shared__ u16 Bs[128 * 64] __attribute__((aligned(16)));
    int lane = threadIdx.x & 63, wid = threadIdx.x >> 6;
    int wr = wid >> 1, wc = wid & 1;
    int l15 = lane & 15, l4 = lane >> 4;

    int L  = blockIdx.x + 8 * blockIdx.y;
    int nL = (L & 7) * 64 + (L >> 3);
    int x_ = nL & 7;
    int y_ = nL >> 3;

    int row0 = y_ * 128, col0 = x_ * 128;
    int lrow = lane >> 3;
    int lcol = (lane & 7) * 8;

    f32x4 acc[4][4] = {};

    for (int kt = 0; kt < K / 64; ++kt) {
        __syncthreads();
        const u16* Abase = A + (size_t)row0 * K + kt * 64;
        const u16* Bbase = Bw + (size_t)col0 * K + kt * 64;
#pragma unroll
        for (int c = 0; c < 4; ++c) {
            int blk = wid * 4 + c;
            GLDS16(Abase + (size_t)(blk * 8 + lrow) * K + lcol, As + blk * 512);
            GLDS16(Bbase + (size_t)(blk * 8 + lrow) * K + lcol, Bs + blk * 512);
        }
        __builtin_amdgcn_s_waitcnt(0);
        __syncthreads();
#pragma unroll
        for (int kk = 0; kk < 2; ++kk) {
            bf16x8 af[4], bfv[4];
#pragma unroll
            for (int i = 0; i < 4; ++i)
                af[i] = frag_ld(As + (wr * 64 + i * 16 + l15) * 64 + kk * 32 + l4 * 8);
#pragma unroll
            for (int j = 0; j < 4; ++j)
                bfv[j] = frag_ld(Bs + (wc * 64 + j * 16 + l15) * 64 + kk * 32 + l4 * 8);
#pragma unroll
            for (int i = 0; i < 4; ++i)
#pragma unroll
                for (int j = 0; j < 4; ++j)
                    acc[i][j] = __builtin_amdgcn_mfma_f32_16x16x32_bf16(
                        af[i], bfv[j], acc[i][j], 0, 0, 0);
        }
    }

#pragma unroll
    for (int j = 0; j < 4; ++j) {
        int c = col0 + wc * 64 + j * 16 + l15;
        float bv = bias[c];
#pragma unroll
        for (int i = 0; i < 4; ++i) {
            int r = row0 + wr * 64 + i * 16 + l4 * 4;
#pragma unroll
            for (int e = 0; e < 4; ++e) {
                size_t idx = (size_t)(r + e) * N + c;
                outf[idx] = acc[i][j][e] + bv + resid[idx];
            }
        }
    }
}

// ---------------- fused attention (R14 structure + T1 XCD swizzle) ----------------
// grid: (S/64, H, B) = 2048 blocks. 4 waves/block, each wave owns 16 q-rows.
// T1: linear block id L remapped nL = (L&7)*256 + L>>3 (bijective, 2048=8*256):
// each head's 32 q-blocks land on one XCD -> K/V stay in that XCD's L2
// (R16: -49.5us, FETCH over-fetch theory confirmed).
// acc col(l15)=q-row, row(l4*4+j)=key; softmax log2-domain, per-lane online,
// one xor{16,32} merge; attn = exp2(a*K2 - off2), nt f32x4 stores.
// Pass 1 KVBLK=128 via K1 aliasing the Ks|Vs union (dead in pass 1); pass-2's
// first top barrier fences the alias. T2 swizzle on K/V tiles. Pt LDS path,
// barrier-disciplined (R5 race lesson; R15: shfl-based P redistribution is
// slower — __shfl = ds_bpermute, same LDS pipe).
__global__ __launch_bounds__(256) void attn_fused(
    const u16* __restrict__ Qb, const u16* __restrict__ Kb,
    const u16* __restrict__ Vt, const int* __restrict__ mask,
    float* __restrict__ attn_out, u16* __restrict__ ctx_out)
{
    __shared__ u16 KV[2 * 64 * 64] __attribute__((aligned(16))); // pass2: Ks|Vs; pass1: K1[128][64]
    __shared__ u16 Pt[64 * 72] __attribute__((aligned(16)));     // bf16 P tile [q][key]
    u16* Ks = KV;
    u16* Vs = KV + 4096;
    u16* K1 = KV;   // pass-1 alias: 128x64 tile (16KB)

    const float K2 = 0.1803368801f;  // 0.125 * log2(e)

    int lane = threadIdx.x & 63, wid = threadIdx.x >> 6;

    // T1 XCD swizzle: decode (bx, h, b) from the remapped linear id
    int L  = blockIdx.x + 32 * (blockIdx.y + 16 * blockIdx.z);
    int nL = (L & 7) * 256 + (L >> 3);
    int bx = nL & 31;
    int h  = (nL >> 5) & 15;
    int b  = nL >> 9;

    int q0 = bx * 64 + wid * 16;
    int l15 = lane & 15, l4 = lane >> 4;
    int lrow = lane >> 3;                       // 0..7
    int lcolsw = (((lane & 7) ^ lrow)) * 8;     // swizzled source col (u16)

    const u16* KbBase = Kb + (size_t)(b * S_) * D_ + h * DK_;
    const u16* VtBase = Vt + ((size_t)((b * H_ + h) * DK_)) * S_;
    const int* mrow = mask + b * S_;

    auto issueK = [&](int c) {        // 64-row tile into Ks (pass 2)
#pragma unroll
        for (int cc = 0; cc < 2; ++cc) {
            int blk = wid * 2 + cc;
            GLDS16(KbBase + (size_t)(c * 64 + blk * 8 + lrow) * D_ + lcolsw,
                   Ks + blk * 512);
        }
    };
    auto issueV = [&](int c) {
#pragma unroll
        for (int cc = 0; cc < 2; ++cc) {
            int blk = wid * 2 + cc;
            GLDS16(VtBase + (size_t)(blk * 8 + lrow) * S_ + c * 64 + lcolsw,
                   Vs + blk * 512);
        }
    };
    auto issueK1 = [&](int e) {       // 128-row tile into K1 (pass 1)
#pragma unroll
        for (int cc = 0; cc < 4; ++cc) {
            int blk = wid * 4 + cc;   // 16 blocks of 8 rows = 128 rows
            GLDS16(KbBase + (size_t)(e * 128 + blk * 8 + lrow) * D_ + lcolsw,
                   K1 + blk * 512);
        }
    };

    // Q fragments (B-operand: row = lane&15 over this wave's 16 q-rows)
    bf16x8 qf[2];
#pragma unroll
    for (int kk = 0; kk < 2; ++kk)
        qf[kk] = frag_ld(Qb + (size_t)(b * S_ + q0 + l15) * D_ +
                         h * DK_ + kk * 32 + l4 * 8);

    float m2_run = -3.0e38f;   // running max of a*K2 (log2 units)
    float l_run  = 0.f;        // running sum of exp2(s2 - m2)

    // ---- PASS 1: per-lane online max / exp2-sum, KVBLK=128, 16 epochs ----
    for (int e = 0; e < 16; ++e) {
        __syncthreads();                 // prior epoch's K1 reads done
        issueK1(e);
        __builtin_amdgcn_s_waitcnt(0);
        __syncthreads();                 // K1(e) ready

#pragma unroll
        for (int half = 0; half < 2; ++half) {
            int kbase = e * 128 + half * 64;     // key base of this 64-key half
            const u16* Kh = K1 + half * 64 * 64; // rows half*64..+63

            int4 mv[4];
#pragma unroll
            for (int n = 0; n < 4; ++n)
                mv[n] = *reinterpret_cast<const int4*>(mrow + kbase + n * 16 + l4 * 4);

            bf16x8 kf[4][2];
#pragma unroll
            for (int n = 0; n < 4; ++n)
#pragma unroll
                for (int kk = 0; kk < 2; ++kk)
                    kf[n][kk] = frag_ld(&Kh[swzRC(n * 16 + l15, kk * 32 + l4 * 8)]);

            f32x4 a[4] = {};
#pragma unroll
            for (int n = 0; n < 4; ++n) {
                a[n] = __builtin_amdgcn_mfma_f32_16x16x32_bf16(kf[n][0], qf[0], a[n], 0, 0, 0);
                a[n] = __builtin_amdgcn_mfma_f32_16x16x32_bf16(kf[n][1], qf[1], a[n], 0, 0, 0);
            }
            float s2[4][4];
            float mxn[4];
#pragma unroll
            for (int n = 0; n < 4; ++n) {
                int mm[4] = {mv[n].x, mv[n].y, mv[n].z, mv[n].w};
#pragma unroll
                for (int j = 0; j < 4; ++j)
                    s2[n][j] = mm[j] ? a[n][j] * K2 : -1.0e9f;
                mxn[n] = fmaxf(fmaxf(s2[n][0], s2[n][1]), fmaxf(s2[n][2], s2[n][3]));
            }
            float mx = fmaxf(fmaxf(mxn[0], mxn[1]), fmaxf(mxn[2], mxn[3]));
            float mnew = fmaxf(m2_run, mx);
            float en[4];
#pragma unroll
            for (int n = 0; n < 4; ++n)
                en[n] = (__builtin_amdgcn_exp2f(s2[n][0] - mnew) +
                         __builtin_amdgcn_exp2f(s2[n][1] - mnew)) +
                        (__builtin_amdgcn_exp2f(s2[n][2] - mnew) +
                         __builtin_amdgcn_exp2f(s2[n][3] - mnew));
            float add = (en[0] + en[1]) + (en[2] + en[3]);
            l_run = l_run * __builtin_amdgcn_exp2f(m2_run - mnew) + add;
            m2_run = mnew;
        }
    }

    // cross-lane merge over the key-split lanes (xor 16, 32), then fold 1/l:
    // off2 = m2 + log2(l)  =>  P = exp2(a*K2 - off2)
#pragma unroll
    for (int off = 16; off <= 32; off <<= 1) {
        float mo = __shfl_xor(m2_run, off);
        float lo = __shfl_xor(l_run, off);
        float mn = fmaxf(m2_run, mo);
        l_run = l_run * __builtin_amdgcn_exp2f(m2_run - mn) +
                lo * __builtin_amdgcn_exp2f(mo - mn);
        m2_run = mn;
    }
    float off2 = m2_run + __builtin_amdgcn_logf(l_run);

    f32x4 cacc[4] = {};

    // ---- PASS 2: recompute, write attn (nt f32x4), Pt, barrier, PV ----
    // First top barrier also fences the K1 -> Ks/Vs alias (pass-1 reads done).
    for (int c = 0; c < 32; ++c) {
        __syncthreads();                 // prior Ks/Vs/Pt reads done
        issueK(c);
        issueV(c);
        __builtin_amdgcn_s_waitcnt(0);
        __syncthreads();                 // Ks/Vs(c) ready

        int4 mv[4];
#pragma unroll
        for (int n = 0; n < 4; ++n)
            mv[n] = *reinterpret_cast<const int4*>(mrow + c * 64 + n * 16 + l4 * 4);

        bf16x8 kf[4][2];
#pragma unroll
        for (int n = 0; n < 4; ++n)
#pragma unroll
            for (int kk = 0; kk < 2; ++kk)
                kf[n][kk] = frag_ld(&Ks[swzRC(n * 16 + l15, kk * 32 + l4 * 8)]);

        {
            f32x4 a[4] = {};
#pragma unroll
            for (int n = 0; n < 4; ++n) {
                a[n] = __builtin_amdgcn_mfma_f32_16x16x32_bf16(kf[n][0], qf[0], a[n], 0, 0, 0);
                a[n] = __builtin_amdgcn_mfma_f32_16x16x32_bf16(kf[n][1], qf[1], a[n], 0, 0, 0);
            }
            int qrow = q0 + l15;
            float* arow = attn_out + ((size_t)((b * H_ + h) * S_ + qrow)) * S_ + c * 64;
            u16* prow = Pt + (wid * 16 + l15) * 72;
#pragma unroll
            for (int n = 0; n < 4; ++n) {
                int mm[4] = {mv[n].x, mv[n].y, mv[n].z, mv[n].w};
                f32x4 at;
                float av[4];
#pragma unroll
                for (int j = 0; j < 4; ++j) {
                    float t = __builtin_amdgcn_exp2f(a[n][j] * K2 - off2);
                    av[j] = mm[j] ? t : 0.0f;
                }
                at[0] = av[0]; at[1] = av[1]; at[2] = av[2]; at[3] = av[3];
                __builtin_nontemporal_store(
                    at, reinterpret_cast<f32x4*>(arow + n * 16 + l4 * 4));
                ushort4 pw;
                pw.x = f2b(av[0]); pw.y = f2b(av[1]);
                pw.z = f2b(av[2]); pw.w = f2b(av[3]);
                *reinterpret_cast<ushort4*>(prow + n * 16 + l4 * 4) = pw;
            }
        }

        // Barrier-discipline Pt: all P writes land before any PV read.
        __syncthreads();

        // PV: ctx[q][d] += P[q][key] * Vt[d][key]
#pragma unroll
        for (int kk = 0; kk < 2; ++kk) {
            bf16x8 pa = frag_ld(Pt + (wid * 16 + l15) * 72 + kk * 32 + l4 * 8);
#pragma unroll
            for (int n = 0; n < 4; ++n) {
                bf16x8 vb = frag_ld(&Vs[swzRC(n * 16 + l15, kk * 32 + l4 * 8)]);
                cacc[n] = __builtin_amdgcn_mfma_f32_16x16x32_bf16(
                    pa, vb, cacc[n], 0, 0, 0);
            }
        }
    }

    // write ctx (bf16, [b][q][h*64+d]); C/D: col(l15)=d, row(l4*4+j)=q
#pragma unroll
    for (int n = 0; n < 4; ++n)
#pragma unroll
        for (int j = 0; j < 4; ++j)
            ctx_out[(size_t)(b * S_ + q0 + l4 * 4 + j) * D_ +
                    h * DK_ + n * 16 + l15] = f2b(cacc[n][j]);
}

// ---------------- LayerNorm ----------------
__global__ __launch_bounds__(256) void ln_kernel(
    const float* __restrict__ X, const float* __restrict__ gamma,
    const float* __restrict__ beta, float* __restrict__ out)
{
    int row = blockIdx.x;
    int t = threadIdx.x;
    float4 v = *reinterpret_cast<const float4*>(X + (size_t)row * D_ + t * 4);
    float s = v.x + v.y + v.z + v.w;
    float ss = v.x * v.x + v.y * v.y + v.z * v.z + v.w * v.w;
#pragma unroll
    for (int o = 1; o < 64; o <<= 1) {
        s += __shfl_xor(s, o);
        ss += __shfl_xor(ss, o);
    }
    __shared__ float red[8];
    int wid = t >> 6, lane = t & 63;
    if (lane == 0) { red[wid] = s; red[wid + 4] = ss; }
    __syncthreads();
    s = red[0] + red[1] + red[2] + red[3];
    ss = red[4] + red[5] + red[6] + red[7];
    float mu = s * (1.0f / D_);
    float var = ss * (1.0f / D_) - mu * mu;
    float rs = rsqrtf(var + 1e-5f);
    float4 g = *reinterpret_cast<const float4*>(gamma + t * 4);
    float4 be = *reinterpret_cast<const float4*>(beta + t * 4);
    f32x4 o4;
    o4[0] = (v.x - mu) * rs * g.x + be.x;
    o4[1] = (v.y - mu) * rs * g.y + be.y;
    o4[2] = (v.z - mu) * rs * g.z + be.z;
    o4[3] = (v.w - mu) * rs * g.w + be.w;
    __builtin_nontemporal_store(
        o4, reinterpret_cast<f32x4*>(out + (size_t)row * D_ + t * 4));
}

// ---------------- launch ----------------
extern "C" void kernel_launch(void* const* d_in, const int* in_sizes, int n_in,
                              void* d_out, int out_size, void* d_ws, size_t ws_size,
                              hipStream_t stream)
{
    const float* query = (const float*)d_in[0];
    const float* key   = (const float*)d_in[1];
    const float* value = (const float*)d_in[2];
    const int*   mask  = (const int*)d_in[3];
    const float* Wq = (const float*)d_in[4];
    const float* bq = (const float*)d_in[5];
    const float* Wk = (const float*)d_in[6];
    const float* bk = (const float*)d_in[7];
    const float* Wv = (const float*)d_in[8];
    const float* bv = (const float*)d_in[9];
    const float* Wo = (const float*)d_in[10];
    const float* bo = (const float*)d_in[11];
    const float* gamma = (const float*)d_in[12];
    const float* beta  = (const float*)d_in[13];

    char* w = (char*)d_ws;
    const size_t MB = 1024 * 1024;
    u16* xq = (u16*)(w);              // 16MB  (dead after QKV-proj; reused for ctx)
    u16* xk = (u16*)(w + 16 * MB);    // 16MB  (dead after QKV-proj; reused for xf)
    u16* xv = (u16*)(w + 32 * MB);    // 16MB  (dead after QKV-proj; reused for xf)
    u16* wq = (u16*)(w + 48 * MB);
    u16* wk = (u16*)(w + 50 * MB);
    u16* wv = (u16*)(w + 52 * MB);
    u16* wo = (u16*)(w + 54 * MB);
    u16* qb = (u16*)(w + 56 * MB);
    u16* kb = (u16*)(w + 72 * MB);
    u16* vt = (u16*)(w + 88 * MB);
    u16* ctxb = (u16*)(w);            // reuse xq region
    float* xf = (float*)(w + 16 * MB); // reuse xk+xv regions (32MB)

    float* out0 = (float*)d_out;
    float* attn = (float*)d_out + (size_t)B_ * S_ * D_;

    int nBig = MROWS * D_;  // 8388608
    int nW = D_ * D_;       // 1048576

    // inputs q,k,v (grid.y=3) and weights (grid.y=4), each one launch
    dim3 gc1(nBig / 1024, 3);
    cvt_multi<<<gc1, 256, 0, stream>>>(query, xq, key, xk, value, xv, query, xq, nBig);
    dim3 gc2(nW / 1024, 4);
    cvt_multi<<<gc2, 256, 0, stream>>>(Wq, wq, Wk, wk, Wv, wv, Wo, wo, nW);

    dim3 gq(D_ / 128, MROWS / 128, 3);  // fused QKV projections (XCD-swizzled)
    gemm_qkv<<<gq, 256, 0, stream>>>(xq, xk, xv, wq, wk, wv, bq, bk, bv, qb, kb, vt);

    dim3 ga(S_ / 64, H_, B_);           // 2048 blocks, QBLK=64 (T1-swizzled in-kernel)
    attn_fused<<<ga, 256, 0, stream>>>(qb, kb, vt, mask, attn, ctxb);

    dim3 gg(D_ / 128, MROWS / 128);     // XCD-swizzled
    gemm_oproj<<<gg, 256, 0, stream>>>(ctxb, wo, bo, query, xf);
    ln_kernel<<<MROWS, 256, 0, stream>>>(xf, gamma, beta, out0);
}